// Round 1
// baseline (357.400 us; speedup 1.0000x reference)
//
#include <hip/hip_runtime.h>
#include <hip/hip_bf16.h>
#include <math.h>

#define DD 512
#define BM 64
#define LL 4096
#define BB 16

typedef __attribute__((ext_vector_type(8))) short short8;
typedef __attribute__((ext_vector_type(4))) float f32x4;
typedef __attribute__((ext_vector_type(4))) unsigned short us4;

__device__ __forceinline__ unsigned short bf16_rn(float f) {
  unsigned u = __float_as_uint(f);
  u = u + 0x7FFFu + ((u >> 16) & 1u);
  return (unsigned short)(u >> 16);
}
__device__ __forceinline__ float bf16_f(unsigned short h) {
  return __uint_as_float(((unsigned)h) << 16);
}

// ---------------------------------------------------------------------------
// Prep: pack Wq/Wk/Wv (f32 [512][512], layout W[e][d], K-contiguous) into
// MFMA-B-fragment-ready bf16 hi/lo arrays in ws.
// Layout (ushort units): value W[e = fn*16 + (lane&15)][d = kt*32 + (lane>>4)*8 + j]
//   at index ((fn*16 + kt)*64 + lane)*8 + j.
// Per matrix: hi at mat*524288, lo at mat*524288 + 262144. mat: 0=Q,1=K,2=V.
// ---------------------------------------------------------------------------
__global__ void prep_kernel(const float* __restrict__ Wq,
                            const float* __restrict__ Wk,
                            const float* __restrict__ Wv,
                            unsigned short* __restrict__ ws_u16) {
  int id = blockIdx.x * blockDim.x + threadIdx.x;  // 0..98303
  int mat = id >> 15;
  int rem = id & 32767;
  int fn = rem >> 10;
  int kt = (rem >> 6) & 15;
  int ln = rem & 63;
  int e  = fn * 16 + (ln & 15);
  int d0 = kt * 32 + ((ln >> 4) << 3);
  const float* W = (mat == 0) ? Wq : (mat == 1) ? Wk : Wv;
  unsigned short* oh = ws_u16 + (size_t)mat * 524288 + (size_t)rem * 8;
  unsigned short* ol = oh + 262144;
  const float* src = W + (size_t)e * DD + d0;
#pragma unroll
  for (int j = 0; j < 8; ++j) {
    float f = src[j];
    unsigned short h = bf16_rn(f);
    oh[j] = h;
    ol[j] = bf16_rn(f - bf16_f(h));
  }
}

// ---------------------------------------------------------------------------
// Fused GEMM: pre = x . W^T  (per einsum 'bld,ed->ble'), then
//   COLSUM: out[block][e]   = sum_rows tanh(pre + bias[e])            (Q path)
//   else  : out[row]        = sum_e tanh(pre + bias[e]) * wvec[b][e]  (K/V path)
// SPLIT: 3-MFMA bf16 hi/lo emulation (fp32-grade), else single bf16 MFMA.
// Block: 64 rows x 512 cols, 512 threads = 8 waves as 2(M) x 4(N).
// ---------------------------------------------------------------------------
template<bool SPLIT, bool COLSUM>
__global__ void gemm_fused(const float* __restrict__ x,
                           const unsigned short* __restrict__ wf_hi,
                           const unsigned short* __restrict__ wf_lo,
                           const float* __restrict__ bias,
                           const float* __restrict__ wvec,
                           float* __restrict__ out) {
  __shared__ unsigned short xa_hi[BM][40];   // padded stride 40 (80B, 16B-aligned)
  __shared__ unsigned short xa_lo[BM][40];
  __shared__ float redc[2][512];
  __shared__ float redr[4][64];

  const int tid  = threadIdx.x;
  const int lane = tid & 63;
  const int wid  = tid >> 6;
  const int wm   = wid >> 2;   // 0..1
  const int wn   = wid & 3;    // 0..3

  const long gr0 = (long)blockIdx.x * BM;
  const float* xblk = x + gr0 * DD;

  f32x4 acc[2][8] = {};

  // A-frag LDS offsets (ushort units): row = wm*32 + m*16 + (lane&15), k-slot = lane>>4
  const int arow  = wm * 32 + (lane & 15);
  const int aoff0 = arow * 40 + ((lane >> 4) << 3);
  const int aoff1 = aoff0 + 16 * 40;

  // B-frag global offset (ushort units): ((fn*16 + kt)*64 + lane)*8, fn = wn*8 + f
  const int boff = (wn * 8 * 16) * 512 + lane * 8;

  // staging: thread t loads float4 at row (t>>3), col (t&7)*4 of the 64x32 tile
  const int sr = tid >> 3;
  const int sc = (tid & 7) * 4;

  float4 xv = *(const float4*)(xblk + (size_t)sr * DD + sc);  // tile kt=0

  for (int kt = 0; kt < 16; ++kt) {
    __syncthreads();  // previous iteration's LDS reads complete
    us4 h = { bf16_rn(xv.x), bf16_rn(xv.y), bf16_rn(xv.z), bf16_rn(xv.w) };
    *(us4*)&xa_hi[sr][sc] = h;
    if (SPLIT) {
      us4 l = { bf16_rn(xv.x - bf16_f(h.x)), bf16_rn(xv.y - bf16_f(h.y)),
                bf16_rn(xv.z - bf16_f(h.z)), bf16_rn(xv.w - bf16_f(h.w)) };
      *(us4*)&xa_lo[sr][sc] = l;
    }
    __syncthreads();
    if (kt < 15)  // prefetch next tile; hides HBM latency under MFMA phase
      xv = *(const float4*)(xblk + (size_t)sr * DD + (kt + 1) * 32 + sc);

    const unsigned short* xh = &xa_hi[0][0];
    short8 a0h = *(const short8*)(xh + aoff0);
    short8 a1h = *(const short8*)(xh + aoff1);
    short8 a0l, a1l;
    if (SPLIT) {
      const unsigned short* xl = &xa_lo[0][0];
      a0l = *(const short8*)(xl + aoff0);
      a1l = *(const short8*)(xl + aoff1);
    }
    const unsigned short* bh_p = wf_hi + boff + kt * 512;
#pragma unroll
    for (int f = 0; f < 8; ++f) {
      short8 bh = *(const short8*)(bh_p + f * 8192);
      acc[0][f] = __builtin_amdgcn_mfma_f32_16x16x32_bf16(a0h, bh, acc[0][f], 0, 0, 0);
      acc[1][f] = __builtin_amdgcn_mfma_f32_16x16x32_bf16(a1h, bh, acc[1][f], 0, 0, 0);
      if (SPLIT) {
        short8 bl = *(const short8*)(wf_lo + boff + kt * 512 + f * 8192);
        acc[0][f] = __builtin_amdgcn_mfma_f32_16x16x32_bf16(a0l, bh, acc[0][f], 0, 0, 0);
        acc[1][f] = __builtin_amdgcn_mfma_f32_16x16x32_bf16(a1l, bh, acc[1][f], 0, 0, 0);
        acc[0][f] = __builtin_amdgcn_mfma_f32_16x16x32_bf16(a0h, bl, acc[0][f], 0, 0, 0);
        acc[1][f] = __builtin_amdgcn_mfma_f32_16x16x32_bf16(a1h, bl, acc[1][f], 0, 0, 0);
      }
    }
  }

  // ---- epilogue ----  C/D layout: col = lane&15, row = (lane>>4)*4 + i  [m89]
  const int cbase = wn * 128 + (lane & 15);
  float bcol[8];
#pragma unroll
  for (int f = 0; f < 8; ++f) bcol[f] = bias[cbase + f * 16];

  if (COLSUM) {
    float cs[8];
#pragma unroll
    for (int f = 0; f < 8; ++f) {
      float s = 0.f;
#pragma unroll
      for (int m = 0; m < 2; ++m)
#pragma unroll
        for (int i = 0; i < 4; ++i)
          s += tanhf(acc[m][f][i] + bcol[f]);
      cs[f] = s;
    }
#pragma unroll
    for (int f = 0; f < 8; ++f) {   // reduce across row-groups (same col)
      cs[f] += __shfl_xor(cs[f], 16);
      cs[f] += __shfl_xor(cs[f], 32);
    }
    __syncthreads();
    if (lane < 16) {
#pragma unroll
      for (int f = 0; f < 8; ++f) redc[wm][wn * 128 + f * 16 + lane] = cs[f];
    }
    __syncthreads();
    out[(size_t)blockIdx.x * 512 + tid] = redc[0][tid] + redc[1][tid];
  } else {
    const int b = (int)(gr0 >> 12);
    float wv[8];
#pragma unroll
    for (int f = 0; f < 8; ++f)
      wv[f] = wvec ? wvec[b * 512 + cbase + f * 16] : 1.0f;
    float rs[2][4] = {};
#pragma unroll
    for (int f = 0; f < 8; ++f)
#pragma unroll
      for (int m = 0; m < 2; ++m)
#pragma unroll
        for (int i = 0; i < 4; ++i)
          rs[m][i] += tanhf(acc[m][f][i] + bcol[f]) * wv[f];
#pragma unroll
    for (int m = 0; m < 2; ++m)
#pragma unroll
      for (int i = 0; i < 4; ++i) {   // reduce across 16 col-lanes (same row)
        rs[m][i] += __shfl_xor(rs[m][i], 1);
        rs[m][i] += __shfl_xor(rs[m][i], 2);
        rs[m][i] += __shfl_xor(rs[m][i], 4);
        rs[m][i] += __shfl_xor(rs[m][i], 8);
      }
    __syncthreads();
    if ((lane & 15) == 0) {
      int rg = lane >> 4;
#pragma unroll
      for (int m = 0; m < 2; ++m)
#pragma unroll
        for (int i = 0; i < 4; ++i)
          redr[wn][wm * 32 + m * 16 + rg * 4 + i] = rs[m][i];
    }
    __syncthreads();
    if (tid < 64)
      out[gr0 + tid] = redr[0][tid] + redr[1][tid] + redr[2][tid] + redr[3][tid];
  }
}

// q_sum[b][e] = sum over the batch's 64 row-blocks of qpart[block][e]
__global__ void reduce_q(const float* __restrict__ qpart, float* __restrict__ q_sum) {
  int b = blockIdx.x;
  int e = threadIdx.x;
  const float* p = qpart + (size_t)b * 64 * 512 + e;
  float s = 0.f;
  for (int j = 0; j < 64; ++j) s += p[j * 512];
  q_sum[b * 512 + e] = s;
}

// per-batch masked softmax over scaled scores, times sv
__global__ void softmax_out(const float* __restrict__ scores,
                            const float* __restrict__ sv,
                            const int* __restrict__ lens,
                            float* __restrict__ out) {
  const int b = blockIdx.x;
  const int tid = threadIdx.x;   // 256
  const int lane = tid & 63, wid = tid >> 6;
  const int len = lens[b];
  const float scale = 0.04419417382415922f;  // 1/sqrt(512)
  __shared__ float sb[4];
  __shared__ float sb2[4];

  float sreg[16];
  const float* sc = scores + (size_t)b * LL;
#pragma unroll
  for (int j = 0; j < 16; ++j) sreg[j] = sc[tid + j * 256] * scale;

  float m = -1e30f;
#pragma unroll
  for (int j = 0; j < 16; ++j)
    if (tid + j * 256 < len) m = fmaxf(m, sreg[j]);
#pragma unroll
  for (int off = 32; off >= 1; off >>= 1) m = fmaxf(m, __shfl_xor(m, off));
  if (lane == 0) sb[wid] = m;
  __syncthreads();
  m = fmaxf(fmaxf(sb[0], sb[1]), fmaxf(sb[2], sb[3]));

  float s = 0.f;
#pragma unroll
  for (int j = 0; j < 16; ++j)
    if (tid + j * 256 < len) s += expf(sreg[j] - m);
#pragma unroll
  for (int off = 32; off >= 1; off >>= 1) s += __shfl_xor(s, off);
  if (lane == 0) sb2[wid] = s;
  __syncthreads();
  const float inv = 1.f / (sb2[0] + sb2[1] + sb2[2] + sb2[3]);

  const float* svb = sv + (size_t)b * LL;
  float* ob = out + (size_t)b * LL;
#pragma unroll
  for (int j = 0; j < 16; ++j) {
    int l = tid + j * 256;
    ob[l] = (l < len) ? svb[l] * expf(sreg[j] - m) * inv : 0.0f;
  }
}

extern "C" void kernel_launch(void* const* d_in, const int* in_sizes, int n_in,
                              void* d_out, int out_size, void* d_ws, size_t ws_size,
                              hipStream_t stream) {
  const float* x  = (const float*)d_in[0];
  const float* Wk = (const float*)d_in[1];
  const float* bk = (const float*)d_in[2];
  const float* Wq = (const float*)d_in[3];
  const float* bq = (const float*)d_in[4];
  const float* Wv = (const float*)d_in[5];
  const float* bv = (const float*)d_in[6];
  const int* lens = (const int*)d_in[7];
  float* out = (float*)d_out;

  char* ws = (char*)d_ws;
  unsigned short* wfu = (unsigned short*)ws;
  // ushort-unit offsets into packed-W region (prep order: 0=Q,1=K,2=V)
  const size_t WQ_HI = 0, WQ_LO = 262144;
  const size_t WK_HI = 524288, WK_LO = 786432;
  const size_t WV_HI = 1048576;
  float* qpart  = (float*)(ws + 3u * 1024 * 1024);            // [1024][512] f32, 2 MB
  float* q_sum  = (float*)(ws + 5u * 1024 * 1024);            // [16][512]
  float* sv     = (float*)(ws + 5u * 1024 * 1024 + 32768);    // [16][4096]
  float* scores = (float*)(ws + 5u * 1024 * 1024 + 32768 + 262144);  // [16][4096]

  prep_kernel<<<384, 256, 0, stream>>>(Wq, Wk, Wv, wfu);
  // Q: split (accurate), column-sum -> per-block partials
  gemm_fused<true, true><<<1024, 512, 0, stream>>>(x, wfu + WQ_HI, wfu + WQ_LO, bq, nullptr, qpart);
  reduce_q<<<16, 512, 0, stream>>>(qpart, q_sum);
  // V: single bf16 MFMA, plain row-sum
  gemm_fused<false, false><<<1024, 512, 0, stream>>>(x, wfu + WV_HI, nullptr, bv, nullptr, sv);
  // K: split, row-sum weighted by q_sum
  gemm_fused<true, false><<<1024, 512, 0, stream>>>(x, wfu + WK_HI, wfu + WK_LO, bk, q_sum, scores);
  softmax_out<<<16, 256, 0, stream>>>(scores, sv, lens, out);
}